// Round 2
// baseline (169.148 us; speedup 1.0000x reference)
//
#include <hip/hip_runtime.h>

typedef short short4v __attribute__((ext_vector_type(4)));
typedef short short8v __attribute__((ext_vector_type(8)));
typedef float float4v __attribute__((ext_vector_type(4)));
typedef unsigned short u16;

#define NB 2
#define NL 2048
#define NS 2048
#define NH 8
#define NE 64
#define HE (NH*NE)   // 512
#define NLT (NL/64)  // 32 l-tiles per (b,h)

static __device__ __forceinline__ u16 f2bf(float x) {
  union { float f; unsigned u; } v; v.f = x;
  unsigned r = v.u + 0x7FFFu + ((v.u >> 16) & 1u);   // RNE
  return (u16)(r >> 16);
}

// One workgroup = one (b, h, 64-row l-tile). 4 waves, each owns 16 l-rows.
// Inputs/outputs are FP32 (reference dtype); converted to bf16 in-register
// during LDS staging. S swept in 64-wide tiles: ST = K_tile * Q^T via
// 16x16x32 MFMA (C-layout row l=lane&15, s=quad*4+reg == A-operand layout of
// 16x16x16 MFMA), so relu^2/exp feed PV directly, no LDS round-trip for P.
// Softmax uses m=0 (|qk|*scale <~ 7 for N(0,1) data); denom is deferred
// per-lane partials + 2 shfl_xor.
__global__ __launch_bounds__(256, 2)
void assa_fwd(const float* __restrict__ qp, const float* __restrict__ kp,
              const float* __restrict__ vp, const float* __restrict__ a1p,
              const float* __restrict__ a2p, float* __restrict__ op)
{
  // K tile row-major [s][e] bf16, 16B-chunk XOR swizzle: K[s][e] at
  //   lds_k[s*64 + ((e>>3) ^ (s&7))*8 + (e&7)]
  __shared__ u16 lds_k[64*64];
  // V tile transposed [e][s] bf16, same swizzle: V[s][e] at
  //   lds_vt[e*64 + ((s>>3) ^ (e&7))*8 + (s&7)]
  __shared__ u16 lds_vt[64*64];

  const int tid  = threadIdx.x;
  const int wv   = tid >> 6;
  const int lane = tid & 63;
  const int ln15 = lane & 15;
  const int ln7  = lane & 7;
  const int quad = lane >> 4;

  const int bid = blockIdx.x;
  const int lt  = bid & (NLT - 1);
  const int bh  = bid / NLT;
  const int h   = bh & (NH - 1);
  const int b   = bh >> 3;

  const int lbase = lt * 64 + wv * 16;

  // Q B-fragments (B[k=e][n=l=lane&15]), 2 k-steps over E=64.
  short8v qf0, qf1;
  {
    const float* qrow = qp + ((size_t)(b * NL + lbase + ln15)) * HE + h * NE;
    #pragma unroll
    for (int j = 0; j < 8; ++j) {
      qf0[j] = (short)f2bf(qrow[quad * 8 + j]);
      qf1[j] = (short)f2bf(qrow[32 + quad * 8 + j]);
    }
  }

  const size_t kvb = (size_t)b * NS * HE + h * NE;
  const float* kb = kp + kvb;
  const float* vb = vp + kvb;

  float4v acc_s[4], acc_d[4];
  #pragma unroll
  for (int t = 0; t < 4; ++t)
    #pragma unroll
    for (int r = 0; r < 4; ++r) { acc_s[t][r] = 0.0f; acc_d[t][r] = 0.0f; }

  float l_part = 0.0f;  // partial softmax denom for row l=ln15

  for (int st = 0; st < NS / 64; ++st) {
    const int s0 = st * 64;
    __syncthreads();  // previous iteration's LDS reads complete

    // ---- stage K tile: wave wv covers s rows [16wv,16wv+16) ----
    {
      const int rsub = lane >> 3;       // 0..7
      const int cg   = ln7 ^ rsub;      // global 8-elem chunk (swizzle at load)
      #pragma unroll
      for (int i = 0; i < 2; ++i) {
        const int srow = wv * 16 + i * 8 + rsub;       // srow&7 == rsub
        const float* src = kb + (size_t)(s0 + srow) * HE + cg * 8;
        float4 x0 = *(const float4*)(src);
        float4 x1 = *(const float4*)(src + 4);
        u16 c[8];
        c[0] = f2bf(x0.x); c[1] = f2bf(x0.y); c[2] = f2bf(x0.z); c[3] = f2bf(x0.w);
        c[4] = f2bf(x1.x); c[5] = f2bf(x1.y); c[6] = f2bf(x1.z); c[7] = f2bf(x1.w);
        *(int4*)(&lds_k[srow * 64 + ln7 * 8]) = *(const int4*)c;  // stored chunk = cg^(s&7)
      }
    }
    // ---- stage V transposed: coalesced scalar loads, vector LDS writes ----
    {
      const float* vcol = vb + (size_t)(s0 + wv * 16) * HE + lane;  // e = lane
      unsigned vr[8];
      #pragma unroll
      for (int jj = 0; jj < 8; ++jj) {
        unsigned lo = f2bf(vcol[(2 * jj) * HE]);
        unsigned hi = f2bf(vcol[(2 * jj + 1) * HE]);
        vr[jj] = lo | (hi << 16);
      }
      #pragma unroll
      for (int i = 0; i < 2; ++i) {
        const int cs = (2 * wv + i) ^ ln7;             // swizzled s-chunk
        int4 t4 = make_int4((int)vr[4 * i + 0], (int)vr[4 * i + 1],
                            (int)vr[4 * i + 2], (int)vr[4 * i + 3]);
        *(int4*)(&lds_vt[lane * 64 + cs * 8]) = t4;
      }
    }
    __syncthreads();

    // ---- compute: 4 s-subtiles of 16 ----
    #pragma unroll
    for (int u = 0; u < 4; ++u) {
      float4v sa; sa[0] = 0.0f; sa[1] = 0.0f; sa[2] = 0.0f; sa[3] = 0.0f;
      // A-frags: K[s=u*16+ln15][e=ks*32+quad*8+j], swizzled chunk reads
      short8v kf0 = *(const short8v*)(&lds_k[(u * 16 + ln15) * 64 + ((quad ^ ln7) * 8)]);
      short8v kf1 = *(const short8v*)(&lds_k[(u * 16 + ln15) * 64 + (((4 + quad) ^ ln7) * 8)]);
      sa = __builtin_amdgcn_mfma_f32_16x16x32_bf16(kf0, qf0, sa, 0, 0, 0);
      sa = __builtin_amdgcn_mfma_f32_16x16x32_bf16(kf1, qf1, sa, 0, 0, 0);
      // sa: lane holds scores^T[s = s0+16u+quad*4+r][l = ln15]

      short4v as, ad;
      #pragma unroll
      for (int r = 0; r < 4; ++r) {
        float sc = sa[r] * 0.125f;          // 1/sqrt(64)
        float rl = sc > 0.0f ? sc : 0.0f;
        float ps = rl * rl;                  // relu^2 branch
        float pd = __expf(sc);               // softmax numerator (m=0)
        l_part += pd;
        as[r] = (short)f2bf(ps);
        ad[r] = (short)f2bf(pd);
      }
      // as/ad ARE the 16x16x16 A-fragments for k-step u (in-register match)
      #pragma unroll
      for (int t = 0; t < 4; ++t) {
        short4v vf = *(const short4v*)(&lds_vt[(t * 16 + ln15) * 64 +
                        (((2 * u + (quad >> 1)) ^ ln7) * 8) + (quad & 1) * 4]);
        acc_s[t] = __builtin_amdgcn_mfma_f32_16x16x16bf16_1k(as, vf, acc_s[t], 0, 0, 0);
        acc_d[t] = __builtin_amdgcn_mfma_f32_16x16x16bf16_1k(ad, vf, acc_d[t], 0, 0, 0);
      }
    }
  }

  // full softmax denominator for row l=ln15: sum the 4 quad partials
  l_part += __shfl_xor(l_part, 16, 64);
  l_part += __shfl_xor(l_part, 32, 64);

  const float a1v = a1p[0];
  const float a2v = a2p[0];
  const float w1 = __expf(a1v), w2 = __expf(a2v);
  const float al1 = w1 / (w1 + w2);
  const float al2 = w2 / (w1 + w2);

  // acc rows are l_local = quad*4 + r; fetch their denoms by shuffle
  float c_d[4];
  #pragma unroll
  for (int r = 0; r < 4; ++r) {
    float ls = __shfl(l_part, quad * 4 + r, 64);
    c_d[r] = al2 / ls;
  }

  #pragma unroll
  for (int t = 0; t < 4; ++t) {
    #pragma unroll
    for (int r = 0; r < 4; ++r) {
      float val = al1 * acc_s[t][r] + c_d[r] * acc_d[t][r];
      const int l = lbase + quad * 4 + r;
      const int e = t * 16 + ln15;
      op[((size_t)(b * NL + l)) * HE + h * NE + e] = val;
    }
  }
}

extern "C" void kernel_launch(void* const* d_in, const int* in_sizes, int n_in,
                              void* d_out, int out_size, void* d_ws, size_t ws_size,
                              hipStream_t stream) {
  const float* q  = (const float*)d_in[0];
  const float* k  = (const float*)d_in[1];
  const float* v  = (const float*)d_in[2];
  const float* a1 = (const float*)d_in[3];
  const float* a2 = (const float*)d_in[4];
  float* out = (float*)d_out;
  (void)in_sizes; (void)n_in; (void)out_size; (void)d_ws; (void)ws_size;
  dim3 grid(NB * NH * NLT);   // 512 workgroups
  assa_fwd<<<grid, dim3(256), 0, stream>>>(q, k, v, a1, a2, out);
}

// Round 3
// 131.054 us; speedup vs baseline: 1.2907x; 1.2907x over previous
//
#include <hip/hip_runtime.h>

typedef short short4v __attribute__((ext_vector_type(4)));
typedef short short8v __attribute__((ext_vector_type(8)));
typedef float float4v __attribute__((ext_vector_type(4)));
typedef unsigned short u16;

#define NB 2
#define NL 2048
#define NS 2048
#define NH 8
#define NE 64
#define HE (NH*NE)   // 512
#define NLT (NL/64)  // 32 l-tiles per (b,h)
#define NST (NS/64)  // 32 s-tiles

// pack two fp32 -> one dword of two bf16 (round-to-nearest, half-up):
// 2 adds + 1 v_perm_b32. Tie-vs-RNE difference is half-ULP on exact ties only.
static __device__ __forceinline__ unsigned pk2bf(float a, float b) {
  union { float f; unsigned u; } x, y; x.f = a; y.f = b;
  return __builtin_amdgcn_perm(y.u + 0x8000u, x.u + 0x8000u, 0x07060302u);
}

// One workgroup = one (b, h, 64-row l-tile). 4 waves, each owns 16 l-rows.
// FP32 I/O, bf16 MFMA compute. ST = K_tile*Q^T via 16x16x32 MFMA (C-layout
// row l=lane&15, s=quad*4+reg == A-operand layout of 16x16x16 MFMA) so
// relu^2/exp feed PV in-register. Softmax m=0; denom = deferred partials.
// K-loop is register-prefetch pipelined: tile st+1's global loads issue
// right after the LDS-write barrier and complete during compute of st.
__global__ __launch_bounds__(256, 2)
void assa_fwd(const float* __restrict__ qp, const float* __restrict__ kp,
              const float* __restrict__ vp, const float* __restrict__ a1p,
              const float* __restrict__ a2p, float* __restrict__ op)
{
  // K tile row-major [s][e] bf16, 8-elt-chunk XOR swizzle: K[s][e] at
  //   lds_k[s*64 + ((e>>3) ^ (s&7))*8 + (e&7)]
  __shared__ u16 lds_k[64*64];
  // V tile transposed [e][s] bf16, same swizzle: V[s][e] at
  //   lds_vt[e*64 + ((s>>3) ^ (e&7))*8 + (s&7)]
  __shared__ u16 lds_vt[64*64];

  const int tid  = threadIdx.x;
  const int wv   = tid >> 6;
  const int lane = tid & 63;
  const int ln15 = lane & 15;
  const int ln7  = lane & 7;
  const int quad = lane >> 4;

  // bid = lt*16 + bh: all 32 l-tiles of one (b,h) hit the same XCD (mod-8
  // round-robin dispatch) -> per-XCD L2 working set = 2 heads' K/V = 4MB.
  const int bid = blockIdx.x;
  const int bh  = bid & 15;
  const int lt  = bid >> 4;
  const int h   = bh & (NH - 1);
  const int b   = bh >> 3;

  const int lbase = lt * 64 + wv * 16;

  // Q B-fragments (B[k=e=quad*8+j][n=l=ln15]), 2 k-steps over E=64.
  short8v qf0, qf1;
  {
    const float* qrow = qp + ((size_t)(b * NL + lbase + ln15)) * HE + h * NE + quad * 8;
    float4 q0 = *(const float4*)(qrow);
    float4 q1 = *(const float4*)(qrow + 4);
    float4 q2 = *(const float4*)(qrow + 32);
    float4 q3 = *(const float4*)(qrow + 36);
    unsigned d0[4] = { pk2bf(q0.x,q0.y), pk2bf(q0.z,q0.w), pk2bf(q1.x,q1.y), pk2bf(q1.z,q1.w) };
    unsigned d1[4] = { pk2bf(q2.x,q2.y), pk2bf(q2.z,q2.w), pk2bf(q3.x,q3.y), pk2bf(q3.z,q3.w) };
    qf0 = *(const short8v*)d0;
    qf1 = *(const short8v*)d1;
  }

  const size_t kvb = (size_t)b * NS * HE + h * NE;
  const float* kb = kp + kvb;
  const float* vb = vp + kvb;

  const int rsub = lane >> 3;       // 0..7
  const int cg   = ln7 ^ rsub;      // global 8-elt chunk (swizzle at load)
  const float* kpl = kb + (size_t)(wv * 16 + rsub) * HE + cg * 8;
  const float* vpl = vb + (size_t)(wv * 16) * HE + lane;   // e = lane

  float4 kpre[4];
  float  vpre[16];

  // prefetch tile 0
  kpre[0] = *(const float4*)(kpl);
  kpre[1] = *(const float4*)(kpl + 4);
  kpre[2] = *(const float4*)(kpl + 8 * HE);
  kpre[3] = *(const float4*)(kpl + 8 * HE + 4);
  #pragma unroll
  for (int jj = 0; jj < 16; ++jj) vpre[jj] = vpl[(size_t)jj * HE];

  float4v acc_s[4], acc_d[4];
  #pragma unroll
  for (int t = 0; t < 4; ++t)
    #pragma unroll
    for (int r = 0; r < 4; ++r) { acc_s[t][r] = 0.0f; acc_d[t][r] = 0.0f; }

  float l_part = 0.0f;  // partial softmax denom for row l=ln15

  for (int st = 0; st < NST; ++st) {
    __syncthreads();  // previous iteration's LDS reads complete

    // ---- commit prefetched tile to LDS ----
    #pragma unroll
    for (int i = 0; i < 2; ++i) {
      const int srow = wv * 16 + i * 8 + rsub;       // srow&7 == rsub
      unsigned kd[4] = { pk2bf(kpre[2*i].x, kpre[2*i].y), pk2bf(kpre[2*i].z, kpre[2*i].w),
                         pk2bf(kpre[2*i+1].x, kpre[2*i+1].y), pk2bf(kpre[2*i+1].z, kpre[2*i+1].w) };
      *(int4*)(&lds_k[srow * 64 + ln7 * 8]) = *(const int4*)kd;  // stored chunk = cg^(s&7)
    }
    #pragma unroll
    for (int i = 0; i < 2; ++i) {
      const int cs = (2 * wv + i) ^ ln7;             // swizzled s-chunk
      unsigned vd[4] = { pk2bf(vpre[8*i+0], vpre[8*i+1]), pk2bf(vpre[8*i+2], vpre[8*i+3]),
                         pk2bf(vpre[8*i+4], vpre[8*i+5]), pk2bf(vpre[8*i+6], vpre[8*i+7]) };
      *(int4*)(&lds_vt[lane * 64 + cs * 8]) = *(const int4*)vd;
    }
    __syncthreads();

    // ---- issue next tile's global loads; they complete during compute ----
    if (st + 1 < NST) {
      const float* kn = kpl + (size_t)(st + 1) * 64 * HE;
      const float* vn = vpl + (size_t)(st + 1) * 64 * HE;
      kpre[0] = *(const float4*)(kn);
      kpre[1] = *(const float4*)(kn + 4);
      kpre[2] = *(const float4*)(kn + 8 * HE);
      kpre[3] = *(const float4*)(kn + 8 * HE + 4);
      #pragma unroll
      for (int jj = 0; jj < 16; ++jj) vpre[jj] = vn[(size_t)jj * HE];
    }

    // ---- compute: 4 s-subtiles of 16 ----
    #pragma unroll
    for (int u = 0; u < 4; ++u) {
      float4v sa; sa[0] = 0.0f; sa[1] = 0.0f; sa[2] = 0.0f; sa[3] = 0.0f;
      // A-frags: K[s=u*16+ln15][e=ks*32+quad*8+j], swizzled chunk reads
      short8v kf0 = *(const short8v*)(&lds_k[(u * 16 + ln15) * 64 + ((quad ^ ln7) * 8)]);
      short8v kf1 = *(const short8v*)(&lds_k[(u * 16 + ln15) * 64 + (((4 + quad) ^ ln7) * 8)]);
      sa = __builtin_amdgcn_mfma_f32_16x16x32_bf16(kf0, qf0, sa, 0, 0, 0);
      sa = __builtin_amdgcn_mfma_f32_16x16x32_bf16(kf1, qf1, sa, 0, 0, 0);
      // sa: lane holds scores^T[s = s0+16u+quad*4+r][l = ln15]

      float ps[4], pd[4];
      #pragma unroll
      for (int r = 0; r < 4; ++r) {
        float sc = sa[r] * 0.125f;          // 1/sqrt(64)
        float rl = sc > 0.0f ? sc : 0.0f;
        ps[r] = rl * rl;                     // relu^2 branch
        pd[r] = __expf(sc);                  // softmax numerator (m=0)
        l_part += pd[r];
      }
      unsigned da[2] = { pk2bf(ps[0], ps[1]), pk2bf(ps[2], ps[3]) };
      unsigned db[2] = { pk2bf(pd[0], pd[1]), pk2bf(pd[2], pd[3]) };
      short4v as = *(const short4v*)da;
      short4v ad = *(const short4v*)db;
      // as/ad ARE the 16x16x16 A-fragments for k-step u (in-register match)
      #pragma unroll
      for (int t = 0; t < 4; ++t) {
        short4v vf = *(const short4v*)(&lds_vt[(t * 16 + ln15) * 64 +
                        (((2 * u + (quad >> 1)) ^ ln7) * 8) + (quad & 1) * 4]);
        acc_s[t] = __builtin_amdgcn_mfma_f32_16x16x16bf16_1k(as, vf, acc_s[t], 0, 0, 0);
        acc_d[t] = __builtin_amdgcn_mfma_f32_16x16x16bf16_1k(ad, vf, acc_d[t], 0, 0, 0);
      }
    }
  }

  // full softmax denominator for row l=ln15: sum the 4 quad partials
  l_part += __shfl_xor(l_part, 16, 64);
  l_part += __shfl_xor(l_part, 32, 64);

  const float a1v = a1p[0];
  const float a2v = a2p[0];
  const float w1 = __expf(a1v), w2 = __expf(a2v);
  const float al1 = w1 / (w1 + w2);
  const float al2 = w2 / (w1 + w2);

  // acc rows are l_local = quad*4 + r; fetch their denoms by shuffle
  float c_d[4];
  #pragma unroll
  for (int r = 0; r < 4; ++r) {
    float ls = __shfl(l_part, quad * 4 + r, 64);
    c_d[r] = al2 / ls;
  }

  #pragma unroll
  for (int t = 0; t < 4; ++t) {
    #pragma unroll
    for (int r = 0; r < 4; ++r) {
      float val = al1 * acc_s[t][r] + c_d[r] * acc_d[t][r];
      const int l = lbase + quad * 4 + r;
      const int e = t * 16 + ln15;
      op[((size_t)(b * NL + l)) * HE + h * NE + e] = val;
    }
  }
}

extern "C" void kernel_launch(void* const* d_in, const int* in_sizes, int n_in,
                              void* d_out, int out_size, void* d_ws, size_t ws_size,
                              hipStream_t stream) {
  const float* q  = (const float*)d_in[0];
  const float* k  = (const float*)d_in[1];
  const float* v  = (const float*)d_in[2];
  const float* a1 = (const float*)d_in[3];
  const float* a2 = (const float*)d_in[4];
  float* out = (float*)d_out;
  (void)in_sizes; (void)n_in; (void)out_size; (void)d_ws; (void)ws_size;
  dim3 grid(NB * NH * NLT);   // 512 workgroups
  assa_fwd<<<grid, dim3(256), 0, stream>>>(q, k, v, a1, a2, out);
}

// Round 4
// 120.522 us; speedup vs baseline: 1.4035x; 1.0874x over previous
//
#include <hip/hip_runtime.h>

typedef short short4v __attribute__((ext_vector_type(4)));
typedef short short8v __attribute__((ext_vector_type(8)));
typedef float float4v __attribute__((ext_vector_type(4)));
typedef unsigned short u16;

#define NB 2
#define NL 2048
#define NS 2048
#define NH 8
#define NE 64
#define HE (NH*NE)    // 512
#define NLT (NL/64)   // 32 l-tiles per (b,h)
#define NST (NS/64)   // 32 s-tiles
#define TILE_U16 4096 // one 64x64 bf16 tile image = 8 KB

// pack two fp32 -> dword of two bf16 (round-to-nearest, half-up)
static __device__ __forceinline__ unsigned pk2bf(float a, float b) {
  union { float f; unsigned u; } x, y; x.f = a; y.f = b;
  return __builtin_amdgcn_perm(y.u + 0x8000u, x.u + 0x8000u, 0x07060302u);
}

#define GLD16(gp, lp) __builtin_amdgcn_global_load_lds( \
    (const __attribute__((address_space(1))) void*)(gp), \
    (__attribute__((address_space(3))) void*)(lp), 16, 0, 0)

// ---------------------------------------------------------------------------
// Pre-pass: convert K,V fp32 -> bf16 tile images in d_ws, laid out in the
// EXACT swizzled byte order the main kernel's LDS wants, so staging becomes a
// pure global_load_lds DMA (no VALU, no LDS-write issue, no transpose).
//   K image slot (srow, p): logical e-chunk c = p ^ (srow&7)   [row-major K]
//   V image slot (e,   p): logical s-chunk sc = p ^ (e&7)      [V transposed]
// ---------------------------------------------------------------------------
__global__ __launch_bounds__(256)
void prepack(const float* __restrict__ kp, const float* __restrict__ vp,
             u16* __restrict__ kimg, u16* __restrict__ vimg)
{
  const int tile = blockIdx.x;          // bh*NST + st
  const int st = tile & (NST - 1);
  const int bh = tile >> 5;
  const int h  = bh & (NH - 1);
  const int b  = bh >> 3;
  const int s0 = st * 64;
  const size_t base = (size_t)b * NS * HE + h * NE;

  u16* kt = kimg + (size_t)tile * TILE_U16;
  u16* vt = vimg + (size_t)tile * TILE_U16;

  // K tile: 512 slots of 8 elts
  for (int slot = threadIdx.x; slot < 512; slot += 256) {
    const int srow = slot >> 3, p = slot & 7, c = p ^ (srow & 7);
    const float* src = kp + base + (size_t)(s0 + srow) * HE + c * 8;
    float4 x0 = *(const float4*)src;
    float4 x1 = *(const float4*)(src + 4);
    unsigned d[4] = { pk2bf(x0.x, x0.y), pk2bf(x0.z, x0.w),
                      pk2bf(x1.x, x1.y), pk2bf(x1.z, x1.w) };
    *(int4*)(kt + slot * 8) = *(const int4*)d;
  }
  // V tile (transposed): 512 slots of 8 elts
  for (int slot = threadIdx.x; slot < 512; slot += 256) {
    const int e = slot >> 3, p = slot & 7, sc = p ^ (e & 7);
    const float* src = vp + base + (size_t)(s0 + sc * 8) * HE + e;
    float v0 = src[0 * HE], v1 = src[1 * HE], v2 = src[2 * HE], v3 = src[3 * HE];
    float v4 = src[4 * HE], v5 = src[5 * HE], v6 = src[6 * HE], v7 = src[7 * HE];
    unsigned d[4] = { pk2bf(v0, v1), pk2bf(v2, v3), pk2bf(v4, v5), pk2bf(v6, v7) };
    *(int4*)(vt + slot * 8) = *(const int4*)d;
  }
}

// ---------------------------------------------------------------------------
// Main: one WG = (b, h, 64-row l-tile); 4 waves x 16 l-rows. Double-buffered
// LDS, ONE barrier per s-tile: DMA(st+1) issues right after the barrier and
// completes during compute(st); the barrier's implicit vmcnt drain at the top
// of st+1 sees it already landed. Compute core identical to verified R2
// (16x16x32 QK -> in-register relu^2/exp -> 16x16x16 PV), scale folded into Q.
// ---------------------------------------------------------------------------
__global__ __launch_bounds__(256, 2)
void assa_fwd(const float* __restrict__ qp, const u16* __restrict__ kimg,
              const u16* __restrict__ vimg, const float* __restrict__ a1p,
              const float* __restrict__ a2p, float* __restrict__ op)
{
  __shared__ __align__(16) u16 ldsb[2][2 * TILE_U16];  // [buf][K | V]

  const int tid  = threadIdx.x;
  const int wv   = tid >> 6;
  const int lane = tid & 63;
  const int ln15 = lane & 15;
  const int ln7  = lane & 7;
  const int quad = lane >> 4;

  // XCD swizzle: all 32 l-tiles of one (b,h) on one XCD
  const int bid = blockIdx.x;
  const int bh  = bid & 15;
  const int lt  = bid >> 4;
  const int h   = bh & (NH - 1);
  const int b   = bh >> 3;

  const int lbase = lt * 64 + wv * 16;

  // Q B-fragments, pre-scaled by 1/sqrt(64) (exact exponent shift in bf16)
  short8v qf0, qf1;
  {
    const float* qrow = qp + ((size_t)(b * NL + lbase + ln15)) * HE + h * NE + quad * 8;
    float4 q0 = *(const float4*)(qrow);
    float4 q1 = *(const float4*)(qrow + 4);
    float4 q2 = *(const float4*)(qrow + 32);
    float4 q3 = *(const float4*)(qrow + 36);
    unsigned d0[4] = { pk2bf(0.125f*q0.x, 0.125f*q0.y), pk2bf(0.125f*q0.z, 0.125f*q0.w),
                       pk2bf(0.125f*q1.x, 0.125f*q1.y), pk2bf(0.125f*q1.z, 0.125f*q1.w) };
    unsigned d1[4] = { pk2bf(0.125f*q2.x, 0.125f*q2.y), pk2bf(0.125f*q2.z, 0.125f*q2.w),
                       pk2bf(0.125f*q3.x, 0.125f*q3.y), pk2bf(0.125f*q3.z, 0.125f*q3.w) };
    qf0 = *(const short8v*)d0;
    qf1 = *(const short8v*)d1;
  }

  const size_t tbase = (size_t)bh * NST;

  float4v acc_s[4], acc_d[4];
  #pragma unroll
  for (int t = 0; t < 4; ++t)
    #pragma unroll
    for (int r = 0; r < 4; ++r) { acc_s[t][r] = 0.0f; acc_d[t][r] = 0.0f; }

  float l_part = 0.0f;

  // DMA one tile (16 KB) into buffer nb: waves 0,1 -> K image, waves 2,3 -> V
  auto dma_tile = [&](int st, int nb) {
    const int half = wv & 1;
    const u16* g;
    u16* l;
    if (wv < 2) {
      g = kimg + (tbase + st) * TILE_U16 + half * 2048 + lane * 8;
      l = &ldsb[nb][half * 2048];
    } else {
      g = vimg + (tbase + st) * TILE_U16 + half * 2048 + lane * 8;
      l = &ldsb[nb][TILE_U16 + half * 2048];
    }
    GLD16(g,        l);
    GLD16(g +  512, l +  512);
    GLD16(g + 1024, l + 1024);
    GLD16(g + 1536, l + 1536);
  };

  dma_tile(0, 0);

  for (int st = 0; st < NST; ++st) {
    __builtin_amdgcn_s_waitcnt(0);   // drain own DMA (barrier requires it anyway)
    __syncthreads();                 // DMA(st) visible; prev reads done
    if (st + 1 < NST) dma_tile(st + 1, (st + 1) & 1);

    const u16* kb_l = ldsb[st & 1];
    const u16* vb_l = ldsb[st & 1] + TILE_U16;

    #pragma unroll
    for (int u = 0; u < 4; ++u) {
      float4v sa; sa[0] = 0.0f; sa[1] = 0.0f; sa[2] = 0.0f; sa[3] = 0.0f;
      short8v kf0 = *(const short8v*)(&kb_l[(u * 16 + ln15) * 64 + ((quad ^ ln7) * 8)]);
      short8v kf1 = *(const short8v*)(&kb_l[(u * 16 + ln15) * 64 + (((4 + quad) ^ ln7) * 8)]);
      sa = __builtin_amdgcn_mfma_f32_16x16x32_bf16(kf0, qf0, sa, 0, 0, 0);
      sa = __builtin_amdgcn_mfma_f32_16x16x32_bf16(kf1, qf1, sa, 0, 0, 0);
      // sa: scores^T[s = 64*st+16u+quad*4+r][l = ln15], already scaled

      float ps[4], pd[4];
      #pragma unroll
      for (int r = 0; r < 4; ++r) {
        float sc = sa[r];
        float rl = sc > 0.0f ? sc : 0.0f;
        ps[r] = rl * rl;
        pd[r] = __expf(sc);
        l_part += pd[r];
      }
      unsigned da[2] = { pk2bf(ps[0], ps[1]), pk2bf(ps[2], ps[3]) };
      unsigned db[2] = { pk2bf(pd[0], pd[1]), pk2bf(pd[2], pd[3]) };
      short4v as = *(const short4v*)da;
      short4v ad = *(const short4v*)db;
      #pragma unroll
      for (int t = 0; t < 4; ++t) {
        short4v vf = *(const short4v*)(&vb_l[(t * 16 + ln15) * 64 +
                        (((2 * u + (quad >> 1)) ^ ln7) * 8) + (quad & 1) * 4]);
        acc_s[t] = __builtin_amdgcn_mfma_f32_16x16x16bf16_1k(as, vf, acc_s[t], 0, 0, 0);
        acc_d[t] = __builtin_amdgcn_mfma_f32_16x16x16bf16_1k(ad, vf, acc_d[t], 0, 0, 0);
      }
    }
  }

  l_part += __shfl_xor(l_part, 16, 64);
  l_part += __shfl_xor(l_part, 32, 64);

  const float w1 = __expf(a1p[0]), w2 = __expf(a2p[0]);
  const float al1 = w1 / (w1 + w2);
  const float al2 = w2 / (w1 + w2);

  float c_d[4];
  #pragma unroll
  for (int r = 0; r < 4; ++r) {
    float ls = __shfl(l_part, quad * 4 + r, 64);
    c_d[r] = al2 / ls;
  }

  #pragma unroll
  for (int t = 0; t < 4; ++t) {
    #pragma unroll
    for (int r = 0; r < 4; ++r) {
      float val = al1 * acc_s[t][r] + c_d[r] * acc_d[t][r];
      const int l = lbase + quad * 4 + r;
      const int e = t * 16 + ln15;
      op[((size_t)(b * NL + l)) * HE + h * NE + e] = val;
    }
  }
}

extern "C" void kernel_launch(void* const* d_in, const int* in_sizes, int n_in,
                              void* d_out, int out_size, void* d_ws, size_t ws_size,
                              hipStream_t stream) {
  const float* q  = (const float*)d_in[0];
  const float* k  = (const float*)d_in[1];
  const float* v  = (const float*)d_in[2];
  const float* a1 = (const float*)d_in[3];
  const float* a2 = (const float*)d_in[4];
  float* out = (float*)d_out;
  (void)in_sizes; (void)n_in; (void)out_size; (void)ws_size;

  u16* kimg = (u16*)d_ws;                                         // 4 MB
  u16* vimg = kimg + (size_t)NB * NH * NST * TILE_U16;            // 4 MB

  prepack<<<dim3(NB * NH * NST), dim3(256), 0, stream>>>(k, v, kimg, vimg);
  assa_fwd<<<dim3(NB * NH * NLT), dim3(256), 0, stream>>>(q, kimg, vimg, a1, a2, out);
}

// Round 5
// 117.162 us; speedup vs baseline: 1.4437x; 1.0287x over previous
//
#include <hip/hip_runtime.h>

typedef short short4v __attribute__((ext_vector_type(4)));
typedef short short8v __attribute__((ext_vector_type(8)));
typedef float float4v __attribute__((ext_vector_type(4)));
typedef unsigned short u16;

#define NB 2
#define NL 2048
#define NS 2048
#define NH 8
#define NE 64
#define HE (NH*NE)    // 512
#define NLT (NL/64)   // 32 l-tiles per (b,h)
#define NST (NS/64)   // 32 s-tiles
#define TILE_U16 4096 // one 64x64 bf16 tile image = 8 KB

// pack two fp32 -> dword of two bf16 (round-to-nearest, half-up)
static __device__ __forceinline__ unsigned pk2bf(float a, float b) {
  union { float f; unsigned u; } x, y; x.f = a; y.f = b;
  return __builtin_amdgcn_perm(y.u + 0x8000u, x.u + 0x8000u, 0x07060302u);
}

#define GLD16(gp, lp) __builtin_amdgcn_global_load_lds( \
    (const __attribute__((address_space(1))) void*)(gp), \
    (__attribute__((address_space(3))) void*)(lp), 16, 0, 0)

// ---------------------------------------------------------------------------
// Pre-pass: convert K,V fp32 -> bf16 tile images in d_ws, in the EXACT
// swizzled byte order the main kernel's LDS wants.
//   K image slot (srow, p): logical e-chunk c = p ^ (srow&7)   [row-major K]
//   V image slot (e,   p): logical s-chunk sc = p ^ (e&7)      [V transposed]
// V transpose goes through LDS (R2's verified staging pattern) so BOTH the
// global read (lane = e, row-contiguous) and the global write (linear copy)
// are fully coalesced — R3's direct scatter-read was the 60 us bottleneck.
// ---------------------------------------------------------------------------
__global__ __launch_bounds__(256)
void prepack(const float* __restrict__ kp, const float* __restrict__ vp,
             u16* __restrict__ kimg, u16* __restrict__ vimg)
{
  __shared__ __align__(16) u16 ldsv[TILE_U16];

  const int tile = blockIdx.x;          // bh*NST + st
  const int st = tile & (NST - 1);
  const int bh = tile >> 5;
  const int h  = bh & (NH - 1);
  const int b  = bh >> 3;
  const int s0 = st * 64;
  const size_t base = (size_t)b * NS * HE + h * NE;
  const int tid  = threadIdx.x;
  const int wv   = tid >> 6;
  const int lane = tid & 63;
  const int ln7  = lane & 7;

  u16* kt = kimg + (size_t)tile * TILE_U16;
  u16* vt = vimg + (size_t)tile * TILE_U16;

  // K: coalesced read (8 lanes span one 256B row), coalesced 16B writes
  for (int slot = tid; slot < 512; slot += 256) {
    const int srow = slot >> 3, p = slot & 7, c = p ^ (srow & 7);
    const float* src = kp + base + (size_t)(s0 + srow) * HE + c * 8;
    float4 x0 = *(const float4*)src;
    float4 x1 = *(const float4*)(src + 4);
    unsigned d[4] = { pk2bf(x0.x, x0.y), pk2bf(x0.z, x0.w),
                      pk2bf(x1.x, x1.y), pk2bf(x1.z, x1.w) };
    *(int4*)(kt + slot * 8) = *(const int4*)d;
  }

  // V: coalesced scalar loads (e = lane, consecutive lanes -> 256B rows),
  // pack pairs, swizzled LDS write = the transpose
  {
    const float* vcol = vp + base + (size_t)(s0 + wv * 16) * HE + lane;
    unsigned vr[8];
    #pragma unroll
    for (int jj = 0; jj < 8; ++jj)
      vr[jj] = pk2bf(vcol[(size_t)(2 * jj) * HE], vcol[(size_t)(2 * jj + 1) * HE]);
    #pragma unroll
    for (int i = 0; i < 2; ++i) {
      const int cs = (2 * wv + i) ^ ln7;   // stored chunk p for logical sc=2wv+i
      int4 t4 = make_int4((int)vr[4*i+0], (int)vr[4*i+1],
                          (int)vr[4*i+2], (int)vr[4*i+3]);
      *(int4*)(&ldsv[lane * 64 + cs * 8]) = t4;
    }
  }
  __syncthreads();
  // linear LDS->global: conflict-free reads, perfectly coalesced writes
  {
    const int4* s = (const int4*)ldsv;
    int4* dst = (int4*)vt;
    dst[tid]       = s[tid];
    dst[tid + 256] = s[tid + 256];
  }
}

// ---------------------------------------------------------------------------
// Main: one WG = (b, h, 64-row l-tile); 4 waves x 16 l-rows. Double-buffered
// LDS, one barrier per s-tile: DMA(st+1) issues right after the barrier and
// completes during compute(st). Compute core identical to verified R2/R3
// (16x16x32 QK -> in-register relu^2/exp -> 16x16x16 PV), scale folded into Q.
// ---------------------------------------------------------------------------
__global__ __launch_bounds__(256, 2)
void assa_fwd(const float* __restrict__ qp, const u16* __restrict__ kimg,
              const u16* __restrict__ vimg, const float* __restrict__ a1p,
              const float* __restrict__ a2p, float* __restrict__ op)
{
  __shared__ __align__(16) u16 ldsb[2][2 * TILE_U16];  // [buf][K | V]

  const int tid  = threadIdx.x;
  const int wv   = tid >> 6;
  const int lane = tid & 63;
  const int ln15 = lane & 15;
  const int ln7  = lane & 7;
  const int quad = lane >> 4;

  // XCD swizzle: all 32 l-tiles of one (b,h) on one XCD
  const int bid = blockIdx.x;
  const int bh  = bid & 15;
  const int lt  = bid >> 4;
  const int h   = bh & (NH - 1);
  const int b   = bh >> 3;

  const int lbase = lt * 64 + wv * 16;

  // Q B-fragments, pre-scaled by 1/sqrt(64) (exact exponent shift)
  short8v qf0, qf1;
  {
    const float* qrow = qp + ((size_t)(b * NL + lbase + ln15)) * HE + h * NE + quad * 8;
    float4 q0 = *(const float4*)(qrow);
    float4 q1 = *(const float4*)(qrow + 4);
    float4 q2 = *(const float4*)(qrow + 32);
    float4 q3 = *(const float4*)(qrow + 36);
    unsigned d0[4] = { pk2bf(0.125f*q0.x, 0.125f*q0.y), pk2bf(0.125f*q0.z, 0.125f*q0.w),
                       pk2bf(0.125f*q1.x, 0.125f*q1.y), pk2bf(0.125f*q1.z, 0.125f*q1.w) };
    unsigned d1[4] = { pk2bf(0.125f*q2.x, 0.125f*q2.y), pk2bf(0.125f*q2.z, 0.125f*q2.w),
                       pk2bf(0.125f*q3.x, 0.125f*q3.y), pk2bf(0.125f*q3.z, 0.125f*q3.w) };
    qf0 = *(const short8v*)d0;
    qf1 = *(const short8v*)d1;
  }

  const size_t tbase = (size_t)bh * NST;

  float4v acc_s[4], acc_d[4];
  #pragma unroll
  for (int t = 0; t < 4; ++t)
    #pragma unroll
    for (int r = 0; r < 4; ++r) { acc_s[t][r] = 0.0f; acc_d[t][r] = 0.0f; }

  float l_part = 0.0f;

  // DMA one tile (16 KB) into buffer nb: waves 0,1 -> K image, waves 2,3 -> V
  auto dma_tile = [&](int st, int nb) {
    const int half = wv & 1;
    const u16* g;
    u16* l;
    if (wv < 2) {
      g = kimg + (tbase + st) * TILE_U16 + half * 2048 + lane * 8;
      l = &ldsb[nb][half * 2048];
    } else {
      g = vimg + (tbase + st) * TILE_U16 + half * 2048 + lane * 8;
      l = &ldsb[nb][TILE_U16 + half * 2048];
    }
    GLD16(g,        l);
    GLD16(g +  512, l +  512);
    GLD16(g + 1024, l + 1024);
    GLD16(g + 1536, l + 1536);
  };

  dma_tile(0, 0);

  for (int st = 0; st < NST; ++st) {
    __builtin_amdgcn_s_waitcnt(0);   // drain own DMA (barrier requires it anyway)
    __syncthreads();                 // DMA(st) visible; prev reads done
    if (st + 1 < NST) dma_tile(st + 1, (st + 1) & 1);

    const u16* kb_l = ldsb[st & 1];
    const u16* vb_l = ldsb[st & 1] + TILE_U16;

    #pragma unroll
    for (int u = 0; u < 4; ++u) {
      float4v sa; sa[0] = 0.0f; sa[1] = 0.0f; sa[2] = 0.0f; sa[3] = 0.0f;
      short8v kf0 = *(const short8v*)(&kb_l[(u * 16 + ln15) * 64 + ((quad ^ ln7) * 8)]);
      short8v kf1 = *(const short8v*)(&kb_l[(u * 16 + ln15) * 64 + (((4 + quad) ^ ln7) * 8)]);
      sa = __builtin_amdgcn_mfma_f32_16x16x32_bf16(kf0, qf0, sa, 0, 0, 0);
      sa = __builtin_amdgcn_mfma_f32_16x16x32_bf16(kf1, qf1, sa, 0, 0, 0);
      // sa: scores^T[s = 64*st+16u+quad*4+r][l = ln15], already scaled

      float ps[4], pd[4];
      #pragma unroll
      for (int r = 0; r < 4; ++r) {
        float sc = sa[r];
        float rl = sc > 0.0f ? sc : 0.0f;
        ps[r] = rl * rl;
        pd[r] = __expf(sc);
        l_part += pd[r];
      }
      unsigned da[2] = { pk2bf(ps[0], ps[1]), pk2bf(ps[2], ps[3]) };
      unsigned db[2] = { pk2bf(pd[0], pd[1]), pk2bf(pd[2], pd[3]) };
      short4v as = *(const short4v*)da;
      short4v ad = *(const short4v*)db;
      #pragma unroll
      for (int t = 0; t < 4; ++t) {
        short4v vf = *(const short4v*)(&vb_l[(t * 16 + ln15) * 64 +
                        (((2 * u + (quad >> 1)) ^ ln7) * 8) + (quad & 1) * 4]);
        acc_s[t] = __builtin_amdgcn_mfma_f32_16x16x16bf16_1k(as, vf, acc_s[t], 0, 0, 0);
        acc_d[t] = __builtin_amdgcn_mfma_f32_16x16x16bf16_1k(ad, vf, acc_d[t], 0, 0, 0);
      }
    }
  }

  l_part += __shfl_xor(l_part, 16, 64);
  l_part += __shfl_xor(l_part, 32, 64);

  const float w1 = __expf(a1p[0]), w2 = __expf(a2p[0]);
  const float al1 = w1 / (w1 + w2);
  const float al2 = w2 / (w1 + w2);

  float c_d[4];
  #pragma unroll
  for (int r = 0; r < 4; ++r) {
    float ls = __shfl(l_part, quad * 4 + r, 64);
    c_d[r] = al2 / ls;
  }

  #pragma unroll
  for (int t = 0; t < 4; ++t) {
    #pragma unroll
    for (int r = 0; r < 4; ++r) {
      float val = al1 * acc_s[t][r] + c_d[r] * acc_d[t][r];
      const int l = lbase + quad * 4 + r;
      const int e = t * 16 + ln15;
      op[((size_t)(b * NL + l)) * HE + h * NE + e] = val;
    }
  }
}

extern "C" void kernel_launch(void* const* d_in, const int* in_sizes, int n_in,
                              void* d_out, int out_size, void* d_ws, size_t ws_size,
                              hipStream_t stream) {
  const float* q  = (const float*)d_in[0];
  const float* k  = (const float*)d_in[1];
  const float* v  = (const float*)d_in[2];
  const float* a1 = (const float*)d_in[3];
  const float* a2 = (const float*)d_in[4];
  float* out = (float*)d_out;
  (void)in_sizes; (void)n_in; (void)out_size; (void)ws_size;

  u16* kimg = (u16*)d_ws;                                         // 4 MB
  u16* vimg = kimg + (size_t)NB * NH * NST * TILE_U16;            // 4 MB

  prepack<<<dim3(NB * NH * NST), dim3(256), 0, stream>>>(k, v, kimg, vimg);
  assa_fwd<<<dim3(NB * NH * NLT), dim3(256), 0, stream>>>(q, kimg, vimg, a1, a2, out);
}

// Round 6
// 112.894 us; speedup vs baseline: 1.4983x; 1.0378x over previous
//
#include <hip/hip_runtime.h>

typedef short short4v __attribute__((ext_vector_type(4)));
typedef short short8v __attribute__((ext_vector_type(8)));
typedef float float4v __attribute__((ext_vector_type(4)));
typedef unsigned short u16;

#define NB 2
#define NL 2048
#define NS 2048
#define NH 8
#define NE 64
#define HE (NH*NE)    // 512
#define NLT (NL/64)   // 32 l-tiles per (b,h)
#define NST (NS/64)   // 32 s-tiles
#define TILE_U16 4096 // one 64x64 bf16 tile image = 8 KB

// pack two fp32 -> dword of two bf16 (round-to-nearest, half-up)
static __device__ __forceinline__ unsigned pk2bf(float a, float b) {
  union { float f; unsigned u; } x, y; x.f = a; y.f = b;
  return __builtin_amdgcn_perm(y.u + 0x8000u, x.u + 0x8000u, 0x07060302u);
}

#define GLD16(gp, lp) __builtin_amdgcn_global_load_lds( \
    (const __attribute__((address_space(1))) void*)(gp), \
    (__attribute__((address_space(3))) void*)(lp), 16, 0, 0)

// K-image swizzle hash: uses s bits {0,1,3} so the permuted QK row set
// (s = 8*(ln15>>2) + (ln15&3) + 4c) still spans all 8 chunk slots.
static __device__ __forceinline__ int fK(int s) { return (s & 3) | ((s >> 1) & 4); }

// ---------------------------------------------------------------------------
// Pre-pass: convert K,V fp32 -> bf16 tile images in d_ws, in the EXACT
// swizzled byte order the main kernel's LDS wants.
//   K image slot (srow, p): logical e-chunk c = p ^ fK(srow)   [row-major K]
//   V image slot (e,   p): logical s-chunk sc = p ^ (e&7)      [V transposed]
// ---------------------------------------------------------------------------
__global__ __launch_bounds__(256)
void prepack(const float* __restrict__ kp, const float* __restrict__ vp,
             u16* __restrict__ kimg, u16* __restrict__ vimg)
{
  __shared__ __align__(16) u16 ldsv[TILE_U16];

  const int tile = blockIdx.x;          // bh*NST + st
  const int st = tile & (NST - 1);
  const int bh = tile >> 5;
  const int h  = bh & (NH - 1);
  const int b  = bh >> 3;
  const int s0 = st * 64;
  const size_t base = (size_t)b * NS * HE + h * NE;
  const int tid  = threadIdx.x;
  const int wv   = tid >> 6;
  const int lane = tid & 63;
  const int ln7  = lane & 7;

  u16* kt = kimg + (size_t)tile * TILE_U16;
  u16* vt = vimg + (size_t)tile * TILE_U16;

  // K: coalesced read (8 lanes span one 256B row), coalesced 16B writes
  for (int slot = tid; slot < 512; slot += 256) {
    const int srow = slot >> 3, p = slot & 7, c = p ^ fK(srow);
    const float* src = kp + base + (size_t)(s0 + srow) * HE + c * 8;
    float4 x0 = *(const float4*)src;
    float4 x1 = *(const float4*)(src + 4);
    unsigned d[4] = { pk2bf(x0.x, x0.y), pk2bf(x0.z, x0.w),
                      pk2bf(x1.x, x1.y), pk2bf(x1.z, x1.w) };
    *(int4*)(kt + slot * 8) = *(const int4*)d;
  }

  // V: coalesced scalar loads (e = lane), pack pairs, swizzled LDS write
  {
    const float* vcol = vp + base + (size_t)(s0 + wv * 16) * HE + lane;
    unsigned vr[8];
    #pragma unroll
    for (int jj = 0; jj < 8; ++jj)
      vr[jj] = pk2bf(vcol[(size_t)(2 * jj) * HE], vcol[(size_t)(2 * jj + 1) * HE]);
    #pragma unroll
    for (int i = 0; i < 2; ++i) {
      const int cs = (2 * wv + i) ^ ln7;   // stored chunk p for logical sc=2wv+i
      int4 t4 = make_int4((int)vr[4*i+0], (int)vr[4*i+1],
                          (int)vr[4*i+2], (int)vr[4*i+3]);
      *(int4*)(&ldsv[lane * 64 + cs * 8]) = t4;
    }
  }
  __syncthreads();
  // linear LDS->global: conflict-free reads, perfectly coalesced writes
  {
    const int4* s = (const int4*)ldsv;
    int4* dst = (int4*)vt;
    dst[tid]       = s[tid];
    dst[tid + 256] = s[tid + 256];
  }
}

// ---------------------------------------------------------------------------
// Main: one WG = (b, h, 64-row l-tile); 4 waves x 16 l-rows. Double-buffered
// LDS, one barrier per s-tile, DMA(st+1) in flight during compute(st).
// QK row-permutation trick: per 32-s-block, two QK calls (c=0,1) load K rows
// s = 32U + 8*(ln15>>2) + (ln15&3) + 4c, so the QK C-layout output lands
// directly as the K=32 PV A-fragment (lane quad q holds s = 32U+8q+j, j=0..7)
// — PV runs on full-rate 16x16x32 MFMA, zero cross-lane exchange.
// ---------------------------------------------------------------------------
__global__ __launch_bounds__(256, 2)
void assa_fwd(const float* __restrict__ qp, const u16* __restrict__ kimg,
              const u16* __restrict__ vimg, const float* __restrict__ a1p,
              const float* __restrict__ a2p, float* __restrict__ op)
{
  __shared__ __align__(16) u16 ldsb[2][2 * TILE_U16];  // [buf][K | V]

  const int tid  = threadIdx.x;
  const int wv   = tid >> 6;
  const int lane = tid & 63;
  const int ln15 = lane & 15;
  const int ln7  = lane & 7;
  const int quad = lane >> 4;

  // XCD swizzle: all 32 l-tiles of one (b,h) on one XCD
  const int bid = blockIdx.x;
  const int bh  = bid & 15;
  const int lt  = bid >> 4;
  const int h   = bh & (NH - 1);
  const int b   = bh >> 3;

  const int lbase = lt * 64 + wv * 16;

  // Q B-fragments, pre-scaled by 1/sqrt(64) (exact exponent shift)
  short8v qf0, qf1;
  {
    const float* qrow = qp + ((size_t)(b * NL + lbase + ln15)) * HE + h * NE + quad * 8;
    float4 q0 = *(const float4*)(qrow);
    float4 q1 = *(const float4*)(qrow + 4);
    float4 q2 = *(const float4*)(qrow + 32);
    float4 q3 = *(const float4*)(qrow + 36);
    unsigned d0[4] = { pk2bf(0.125f*q0.x, 0.125f*q0.y), pk2bf(0.125f*q0.z, 0.125f*q0.w),
                       pk2bf(0.125f*q1.x, 0.125f*q1.y), pk2bf(0.125f*q1.z, 0.125f*q1.w) };
    unsigned d1[4] = { pk2bf(0.125f*q2.x, 0.125f*q2.y), pk2bf(0.125f*q2.z, 0.125f*q2.w),
                       pk2bf(0.125f*q3.x, 0.125f*q3.y), pk2bf(0.125f*q3.z, 0.125f*q3.w) };
    qf0 = *(const short8v*)d0;
    qf1 = *(const short8v*)d1;
  }

  const size_t tbase = (size_t)bh * NST;

  float4v acc_s[4], acc_d[4];
  #pragma unroll
  for (int t = 0; t < 4; ++t)
    #pragma unroll
    for (int r = 0; r < 4; ++r) { acc_s[t][r] = 0.0f; acc_d[t][r] = 0.0f; }

  float l_part = 0.0f;

  // DMA one tile (16 KB) into buffer nb: waves 0,1 -> K image, waves 2,3 -> V
  auto dma_tile = [&](int st, int nb) {
    const int half = wv & 1;
    const u16* g;
    u16* l;
    if (wv < 2) {
      g = kimg + (tbase + st) * TILE_U16 + half * 2048 + lane * 8;
      l = &ldsb[nb][half * 2048];
    } else {
      g = vimg + (tbase + st) * TILE_U16 + half * 2048 + lane * 8;
      l = &ldsb[nb][TILE_U16 + half * 2048];
    }
    GLD16(g,        l);
    GLD16(g +  512, l +  512);
    GLD16(g + 1024, l + 1024);
    GLD16(g + 1536, l + 1536);
  };

  dma_tile(0, 0);

  // QK row permutation pieces (c-independent): row base & swizzle hash
  const int rperm = 8 * (ln15 >> 2) + (ln15 & 3);          // + 32U + 4c
  const int fk    = (ln15 & 3) | (((ln15 >> 2) & 1) << 2); // fK of that row

  for (int st = 0; st < NST; ++st) {
    __builtin_amdgcn_s_waitcnt(0);   // drain own DMA (barrier requires it anyway)
    __syncthreads();                 // DMA(st) visible; prev reads done
    if (st + 1 < NST) dma_tile(st + 1, (st + 1) & 1);

    const u16* kb_l = ldsb[st & 1];
    const u16* vb_l = ldsb[st & 1] + TILE_U16;

    #pragma unroll
    for (int U = 0; U < 2; ++U) {
      // --- QK for one 32-wide s-block, two row-permuted calls c=0,1 ---
      float4v sa0, sa1;
      #pragma unroll
      for (int r = 0; r < 4; ++r) { sa0[r] = 0.0f; sa1[r] = 0.0f; }
      const u16* krow0 = &kb_l[(32 * U + rperm) * 64];
      const u16* krow1 = krow0 + 4 * 64;
      short8v kf00 = *(const short8v*)(krow0 + (quad ^ fk) * 8);
      short8v kf01 = *(const short8v*)(krow0 + ((4 + quad) ^ fk) * 8);
      short8v kf10 = *(const short8v*)(krow1 + (quad ^ fk) * 8);
      short8v kf11 = *(const short8v*)(krow1 + ((4 + quad) ^ fk) * 8);
      sa0 = __builtin_amdgcn_mfma_f32_16x16x32_bf16(kf00, qf0, sa0, 0, 0, 0);
      sa0 = __builtin_amdgcn_mfma_f32_16x16x32_bf16(kf01, qf1, sa0, 0, 0, 0);
      sa1 = __builtin_amdgcn_mfma_f32_16x16x32_bf16(kf10, qf0, sa1, 0, 0, 0);
      sa1 = __builtin_amdgcn_mfma_f32_16x16x32_bf16(kf11, qf1, sa1, 0, 0, 0);
      // lane (quad,l=ln15): sa0[r] = score[s=32U+8q+r][l], sa1[r] = s=32U+8q+4+r

      float ps[8], pd[8];
      #pragma unroll
      for (int r = 0; r < 4; ++r) {
        float s0 = sa0[r], s1 = sa1[r];
        float r0 = s0 > 0.0f ? s0 : 0.0f;
        float r1 = s1 > 0.0f ? s1 : 0.0f;
        ps[r] = r0 * r0;  ps[4 + r] = r1 * r1;
        pd[r] = __expf(s0); pd[4 + r] = __expf(s1);
        l_part += pd[r] + pd[4 + r];
      }
      unsigned da[4] = { pk2bf(ps[0], ps[1]), pk2bf(ps[2], ps[3]),
                         pk2bf(ps[4], ps[5]), pk2bf(ps[6], ps[7]) };
      unsigned db[4] = { pk2bf(pd[0], pd[1]), pk2bf(pd[2], pd[3]),
                         pk2bf(pd[4], pd[5]), pk2bf(pd[6], pd[7]) };
      short8v as8 = *(const short8v*)da;   // A[m=l][k=s-32U] for K=32 PV
      short8v ad8 = *(const short8v*)db;

      #pragma unroll
      for (int t = 0; t < 4; ++t) {
        short8v vf = *(const short8v*)(&vb_l[(t * 16 + ln15) * 64 +
                        (((4 * U + quad) ^ ln7) * 8)]);
        acc_s[t] = __builtin_amdgcn_mfma_f32_16x16x32_bf16(as8, vf, acc_s[t], 0, 0, 0);
        acc_d[t] = __builtin_amdgcn_mfma_f32_16x16x32_bf16(ad8, vf, acc_d[t], 0, 0, 0);
      }
    }
  }

  l_part += __shfl_xor(l_part, 16, 64);
  l_part += __shfl_xor(l_part, 32, 64);

  const float w1 = __expf(a1p[0]), w2 = __expf(a2p[0]);
  const float al1 = w1 / (w1 + w2);
  const float al2 = w2 / (w1 + w2);

  float c_d[4];
  #pragma unroll
  for (int r = 0; r < 4; ++r) {
    float ls = __shfl(l_part, quad * 4 + r, 64);
    c_d[r] = al2 / ls;
  }

  #pragma unroll
  for (int t = 0; t < 4; ++t) {
    #pragma unroll
    for (int r = 0; r < 4; ++r) {
      float val = al1 * acc_s[t][r] + c_d[r] * acc_d[t][r];
      const int l = lbase + quad * 4 + r;
      const int e = t * 16 + ln15;
      op[((size_t)(b * NL + l)) * HE + h * NE + e] = val;
    }
  }
}

extern "C" void kernel_launch(void* const* d_in, const int* in_sizes, int n_in,
                              void* d_out, int out_size, void* d_ws, size_t ws_size,
                              hipStream_t stream) {
  const float* q  = (const float*)d_in[0];
  const float* k  = (const float*)d_in[1];
  const float* v  = (const float*)d_in[2];
  const float* a1 = (const float*)d_in[3];
  const float* a2 = (const float*)d_in[4];
  float* out = (float*)d_out;
  (void)in_sizes; (void)n_in; (void)out_size; (void)ws_size;

  u16* kimg = (u16*)d_ws;                                         // 4 MB
  u16* vimg = kimg + (size_t)NB * NH * NST * TILE_U16;            // 4 MB

  prepack<<<dim3(NB * NH * NST), dim3(256), 0, stream>>>(k, v, kimg, vimg);
  assa_fwd<<<dim3(NB * NH * NLT), dim3(256), 0, stream>>>(q, kimg, vimg, a1, a2, out);
}